// Round 5
// baseline (767.361 us; speedup 1.0000x reference)
//
#include <hip/hip_runtime.h>
#include <hip/hip_bf16.h>
#include <math.h>

#define BB 2
#define NN 512
#define CS 384
#define CZ 128
#define HH 12
#define CATW 2112

#define W_L_CONST 0.57735026919f
#define W_C_HALF 0.11785113019f
#define INV_SQRT_D 0.25f
#define LGP 516   // padded row stride for lg[h][*] (multiple of 4 for float4 alignment)

// ---------------- Kernel 1: projections + rigid apply (2 tokens/block) ----
__global__ void k_proj(const float* __restrict__ s_i,
                       const float* __restrict__ rots,
                       const float* __restrict__ trans,
                       const float* __restrict__ wq,
                       const float* __restrict__ wk,
                       const float* __restrict__ wv,
                       const float* __restrict__ wqp,
                       const float* __restrict__ wkp,
                       const float* __restrict__ wvp,
                       float* __restrict__ qw, float* __restrict__ kw,
                       float* __restrict__ vw, float* __restrict__ tqw,
                       float* __restrict__ tkw, float* __restrict__ tvw) {
  int t0 = blockIdx.x * 2;
  __shared__ float s_row[2][CS];
  __shared__ float praw[2][576];
  __shared__ float R[2][9], T[2][3];
  int tid = threadIdx.x;
  for (int idx = tid; idx < 2 * CS; idx += 256) {
    int tok = idx / CS, c = idx % CS;
    s_row[tok][c] = s_i[(size_t)(t0 + tok) * CS + c];
  }
  if (tid < 18) R[tid / 9][tid % 9] = rots[t0 * 9 + tid];
  if (tid < 6) T[tid / 3][tid % 3] = trans[t0 * 3 + tid];
  __syncthreads();

  for (int f = tid; f < 1152; f += 256) {
    const float* wp;
    int stride;
    if (f < 576) {
      int sel = f / 192, r = f % 192;
      wp = ((sel == 0) ? wq : (sel == 1) ? wk : wv) + r;
      stride = 192;
    } else {
      int g = f - 576;
      if (g < 144)      { wp = wqp + g;        stride = 144; }
      else if (g < 288) { wp = wkp + (g - 144); stride = 144; }
      else              { wp = wvp + (g - 288); stride = 288; }
    }
    float a0 = 0.f, a1 = 0.f;
    #pragma unroll 8
    for (int c = 0; c < CS; c++) {
      float w = wp[(size_t)c * stride];
      a0 += s_row[0][c] * w;
      a1 += s_row[1][c] * w;
    }
    if (f < 576) {
      int sel = f / 192, r = f % 192;
      float* dst = (sel == 0) ? qw : (sel == 1) ? kw : vw;
      dst[(size_t)(t0 + 0) * 192 + r] = a0;
      dst[(size_t)(t0 + 1) * 192 + r] = a1;
    } else {
      int g = f - 576;
      praw[0][g] = a0;
      praw[1][g] = a1;
    }
  }
  __syncthreads();
  for (int idx = tid; idx < 1152; idx += 256) {
    int tok = idx / 576, f = idx % 576;
    int base, r;
    float* dst;
    if (f < 144)      { r = f;       base = 0;   dst = tqw + (size_t)(t0 + tok) * 144; }
    else if (f < 288) { r = f - 144; base = 144; dst = tkw + (size_t)(t0 + tok) * 144; }
    else              { r = f - 288; base = 288; dst = tvw + (size_t)(t0 + tok) * 288; }
    int hp = r / 3, x = r % 3;
    float v0 = praw[tok][base + hp * 3 + 0];
    float v1 = praw[tok][base + hp * 3 + 1];
    float v2 = praw[tok][base + hp * 3 + 2];
    dst[r] = R[tok][x * 3 + 0] * v0 + R[tok][x * 3 + 1] * v1 + R[tok][x * 3 + 2] * v2 + T[tok][x];
  }
}

// ---------------- Kernel 2: pair bias GEMM (z @ wb) -----------------------
// Register-blocked: lane owns one j-row (12 h accumulators in VGPRs),
// wb accessed with wave-uniform indices -> SGPR loads (no lane LDS reads),
// z staged per-wave in LDS c-chunks, read as conflict-free float4.
// grid: 2048 blocks x 256 thr; block = 256 rows (bi = blk>>1, j0 = (blk&1)*256)
__global__ void k_bias(const float* __restrict__ z,
                       const float* __restrict__ wb,
                       float* __restrict__ bw) {
  __shared__ float zt[4][64][33];   // per-wave private tile, padded
  int tid = threadIdx.x, lane = tid & 63, w = tid >> 6;
  int bi = blockIdx.x >> 1;
  int j0 = (blockIdx.x & 1) * 256 + w * 64;
  const float* zbase = z + ((size_t)bi * NN + j0) * CZ;

  float acc[12];
  #pragma unroll
  for (int h = 0; h < 12; h++) acc[h] = 0.f;

  for (int cc = 0; cc < 4; cc++) {
    int c0 = cc * 32;
    // stage 64 rows x 32 c (wave-private; wave-synchronous, no barrier needed)
    #pragma unroll
    for (int i = 0; i < 8; i++) {
      int row = i * 8 + (lane >> 3), cq = lane & 7;
      float4 v = *(const float4*)(zbase + (size_t)row * CZ + c0 + cq * 4);
      *(float4*)&zt[w][row][cq * 4] = v;
    }
    #pragma unroll
    for (int c = 0; c < 32; c += 4) {
      float4 zv = *(const float4*)&zt[w][lane][c];
      const float* w0 = wb + (size_t)(c0 + c) * HH;      // uniform -> s_load
      #pragma unroll
      for (int h = 0; h < 12; h++) acc[h] += zv.x * w0[h];
      #pragma unroll
      for (int h = 0; h < 12; h++) acc[h] += zv.y * w0[12 + h];
      #pragma unroll
      for (int h = 0; h < 12; h++) acc[h] += zv.z * w0[24 + h];
      #pragma unroll
      for (int h = 0; h < 12; h++) acc[h] += zv.w * w0[36 + h];
    }
  }
  // h-major coalesced store: lanes are consecutive j
  #pragma unroll
  for (int h = 0; h < 12; h++)
    bw[((size_t)bi * HH + h) * NN + j0 + lane] = acc[h];
}

// ---------------- Kernel 3: fused logits+softmax+o/o_hp+o_hat ------------
// block per (b,i), 256 threads
__global__ void k_att(const float* __restrict__ z,
                      const float* __restrict__ qw,
                      const float* __restrict__ kw,
                      const float* __restrict__ tqw,
                      const float* __restrict__ tkw,
                      const float* __restrict__ vw,
                      const float* __restrict__ tvw,
                      const float* __restrict__ gamma,
                      const float* __restrict__ rots,
                      const float* __restrict__ trans,
                      const float* __restrict__ bw,
                      float* __restrict__ catm) {
  int bi = blockIdx.x;
  int b = bi / NN;
  __shared__ float lg[HH][LGP];      // logits -> a -> (later) o_hat partial buffer
  __shared__ float scratch[6144];    // opart(1920)+praw(288)+ohp(288) then aT[512][12]
  __shared__ float qrow[192], tqrow[144], gam[HH];
  __shared__ float rm[HH][4], rs[HH][4];
  __shared__ float R[9], T[3];
  int tid = threadIdx.x;
  int lane = tid & 63, wid = tid >> 6;

  const float* bwrow = bw + (size_t)bi * (HH * NN);
  for (int idx = tid; idx < HH * NN; idx += 256)
    lg[idx >> 9][idx & 511] = bwrow[idx];
  for (int idx = tid; idx < 192; idx += 256) qrow[idx] = qw[(size_t)bi * 192 + idx];
  if (tid < 144) tqrow[tid] = tqw[(size_t)bi * 144 + tid];
  if (tid < HH) gam[tid] = gamma[tid];
  if (tid < 9) R[tid] = rots[bi * 9 + tid];
  if (tid < 3) T[tid] = trans[bi * 3 + tid];
  __syncthreads();

  // ---- logits: 6144 tasks = 24 * 256 ----
  for (int s = 0; s < 24; s++) {
    int task = tid + s * 256;
    int j = task / 12, h = task % 12;
    const float4* kd = (const float4*)(kw + ((size_t)(b * NN + j)) * 192 + h * 16);
    float as = 0.f;
    #pragma unroll
    for (int q = 0; q < 4; q++) {
      float4 kv = kd[q];
      as += qrow[h * 16 + q * 4 + 0] * kv.x + qrow[h * 16 + q * 4 + 1] * kv.y +
            qrow[h * 16 + q * 4 + 2] * kv.z + qrow[h * 16 + q * 4 + 3] * kv.w;
    }
    const float4* td = (const float4*)(tkw + ((size_t)(b * NN + j)) * 144 + h * 12);
    float d2 = 0.f;
    #pragma unroll
    for (int q = 0; q < 3; q++) {
      float4 tv = td[q];
      float d0 = tqrow[h * 12 + q * 4 + 0] - tv.x;
      float d1 = tqrow[h * 12 + q * 4 + 1] - tv.y;
      float d2_ = tqrow[h * 12 + q * 4 + 2] - tv.z;
      float d3 = tqrow[h * 12 + q * 4 + 3] - tv.w;
      d2 += d0 * d0 + d1 * d1 + d2_ * d2_ + d3 * d3;
    }
    lg[h][j] = W_L_CONST * (as * INV_SQRT_D + lg[h][j] - W_C_HALF * gam[h] * d2);
  }
  __syncthreads();

  // ---- softmax ----
  #pragma unroll
  for (int h = 0; h < HH; h++) {
    float m = fmaxf(lg[h][tid], lg[h][tid + 256]);
    #pragma unroll
    for (int off = 32; off >= 1; off >>= 1) m = fmaxf(m, __shfl_xor(m, off, 64));
    if (lane == 0) rm[h][wid] = m;
  }
  __syncthreads();
  #pragma unroll
  for (int h = 0; h < HH; h++) {
    float mx = fmaxf(fmaxf(rm[h][0], rm[h][1]), fmaxf(rm[h][2], rm[h][3]));
    float e0 = __expf(lg[h][tid] - mx);
    float e1 = __expf(lg[h][tid + 256] - mx);
    lg[h][tid] = e0;
    lg[h][tid + 256] = e1;
    float s = e0 + e1;
    #pragma unroll
    for (int off = 32; off >= 1; off >>= 1) s += __shfl_xor(s, off, 64);
    if (lane == 0) rs[h][wid] = s;
  }
  __syncthreads();
  #pragma unroll
  for (int h = 0; h < HH; h++) {
    float inv = 1.0f / (rs[h][0] + rs[h][1] + rs[h][2] + rs[h][3]);
    lg[h][tid] *= inv;
    lg[h][tid + 256] *= inv;
  }
  __syncthreads();   // lg now holds a

  float* crow = catm + (size_t)bi * CATW;
  int j0 = wid * 128;   // this wave's j window
  float* opart = scratch;            // [4][480]
  float* praw = scratch + 1920;      // [288]
  float* ohp  = scratch + 2208;      // [288]

  // ---- o / o_hp partials: wave-split over j ----
  for (int t = lane; t < 480; t += 64) {
    const float* src;
    int h, str;
    if (t < 192) { h = t >> 4; src = vw + (size_t)b * NN * 192 + t; str = 192; }
    else { int f = t - 192; h = f / 24; src = tvw + (size_t)b * NN * 288 + f; str = 288; }
    float sum = 0.f;
    for (int jj = 0; jj < 128; jj += 4) {
      float4 av = *(const float4*)&lg[h][j0 + jj];
      sum += av.x * src[(size_t)(j0 + jj + 0) * str]
           + av.y * src[(size_t)(j0 + jj + 1) * str]
           + av.z * src[(size_t)(j0 + jj + 2) * str]
           + av.w * src[(size_t)(j0 + jj + 3) * str];
    }
    opart[wid * 480 + t] = sum;
  }
  __syncthreads();
  for (int t = tid; t < 480; t += 256) {
    float s = opart[t] + opart[480 + t] + opart[960 + t] + opart[1440 + t];
    if (t < 192) crow[1536 + t] = s;
    else praw[t - 192] = s;
  }
  __syncthreads();
  for (int f = tid; f < 288; f += 256) {
    int g = f / 3, x = f % 3;
    float v0 = praw[g * 3 + 0] - T[0];
    float v1 = praw[g * 3 + 1] - T[1];
    float v2 = praw[g * 3 + 2] - T[2];
    float val = R[0 * 3 + x] * v0 + R[1 * 3 + x] * v1 + R[2 * 3 + x] * v2;
    ohp[f] = val;
    crow[1728 + f] = val;
  }
  __syncthreads();
  if (tid < 96) {
    float x0 = ohp[tid * 3 + 0];
    float x1 = ohp[tid * 3 + 1];
    float x2 = ohp[tid * 3 + 2];
    crow[2016 + tid] = sqrtf(x0 * x0 + x1 * x1 + x2 * x2);
  }
  __syncthreads();   // all reads of opart/praw/ohp done; reuse scratch as aT

  // ---- build aT[j][12] for uniform-broadcast reads in the z stream ----
  for (int idx = tid; idx < 6144; idx += 256) {
    int j = idx / 12, h = idx - j * 12;
    scratch[idx] = lg[h][j];
  }
  __syncthreads();

  // ---- o_hat: stream z, half-wave j-split, unroll 4 (4 loads in flight) --
  int hw = lane >> 5, c4 = (lane & 31) * 4;
  float4 acc[HH];
  #pragma unroll
  for (int h = 0; h < HH; h++) acc[h] = make_float4(0.f, 0.f, 0.f, 0.f);
  const float* zr = z + (size_t)bi * NN * CZ;
  for (int stp = 0; stp < 16; stp++) {
    int jb = j0 + stp * 8;
    float4 zv[4];
    #pragma unroll
    for (int u = 0; u < 4; u++)
      zv[u] = *(const float4*)(zr + (size_t)(jb + 2 * u + hw) * CZ + c4);
    #pragma unroll
    for (int u = 0; u < 4; u++) {
      int j = jb + 2 * u + hw;
      float4 A0 = *(const float4*)&scratch[j * 12];
      float4 A1 = *(const float4*)&scratch[j * 12 + 4];
      float4 A2 = *(const float4*)&scratch[j * 12 + 8];
      acc[0].x += A0.x * zv[u].x; acc[0].y += A0.x * zv[u].y; acc[0].z += A0.x * zv[u].z; acc[0].w += A0.x * zv[u].w;
      acc[1].x += A0.y * zv[u].x; acc[1].y += A0.y * zv[u].y; acc[1].z += A0.y * zv[u].z; acc[1].w += A0.y * zv[u].w;
      acc[2].x += A0.z * zv[u].x; acc[2].y += A0.z * zv[u].y; acc[2].z += A0.z * zv[u].z; acc[2].w += A0.z * zv[u].w;
      acc[3].x += A0.w * zv[u].x; acc[3].y += A0.w * zv[u].y; acc[3].z += A0.w * zv[u].z; acc[3].w += A0.w * zv[u].w;
      acc[4].x += A1.x * zv[u].x; acc[4].y += A1.x * zv[u].y; acc[4].z += A1.x * zv[u].z; acc[4].w += A1.x * zv[u].w;
      acc[5].x += A1.y * zv[u].x; acc[5].y += A1.y * zv[u].y; acc[5].z += A1.y * zv[u].z; acc[5].w += A1.y * zv[u].w;
      acc[6].x += A1.z * zv[u].x; acc[6].y += A1.z * zv[u].y; acc[6].z += A1.z * zv[u].z; acc[6].w += A1.z * zv[u].w;
      acc[7].x += A1.w * zv[u].x; acc[7].y += A1.w * zv[u].y; acc[7].z += A1.w * zv[u].z; acc[7].w += A1.w * zv[u].w;
      acc[8].x += A2.x * zv[u].x; acc[8].y += A2.x * zv[u].y; acc[8].z += A2.x * zv[u].z; acc[8].w += A2.x * zv[u].w;
      acc[9].x += A2.y * zv[u].x; acc[9].y += A2.y * zv[u].y; acc[9].z += A2.y * zv[u].z; acc[9].w += A2.y * zv[u].w;
      acc[10].x += A2.z * zv[u].x; acc[10].y += A2.z * zv[u].y; acc[10].z += A2.z * zv[u].z; acc[10].w += A2.z * zv[u].w;
      acc[11].x += A2.w * zv[u].x; acc[11].y += A2.w * zv[u].y; acc[11].z += A2.w * zv[u].z; acc[11].w += A2.w * zv[u].w;
    }
  }
  __syncthreads();   // aT reads complete everywhere; lg reusable as partial buf
  #pragma unroll
  for (int h = 0; h < HH; h++) {
    acc[h].x += __shfl_xor(acc[h].x, 32, 64);
    acc[h].y += __shfl_xor(acc[h].y, 32, 64);
    acc[h].z += __shfl_xor(acc[h].z, 32, 64);
    acc[h].w += __shfl_xor(acc[h].w, 32, 64);
  }
  float* pbuf = &lg[0][0];
  if (lane < 32) {
    #pragma unroll
    for (int h = 0; h < HH; h++)
      *(float4*)&pbuf[wid * 1536 + h * 128 + (lane & 31) * 4] = acc[h];
  }
  __syncthreads();
  #pragma unroll
  for (int s = 0; s < 6; s++) {
    int idx = tid + s * 256;
    crow[idx] = pbuf[idx] + pbuf[1536 + idx] + pbuf[3072 + idx] + pbuf[4608 + idx];
  }
}

// ---------------- Kernel 4: output GEMM, split-K=4, 64x64, 4x4 reg tile ---
#define KCH 528
__global__ void k_gemm(const float* __restrict__ catm,
                       const float* __restrict__ wout,
                       float* __restrict__ pout) {
  __shared__ float As[16][68];
  __shared__ float Bs[16][64];
  int tid = threadIdx.x;
  int n0 = blockIdx.x * 64, m0 = blockIdx.y * 64, kbase = blockIdx.z * KCH;
  int tx = tid & 15, ty = tid >> 4;
  int sm = tid & 63, skk4 = tid >> 6;
  int bkk = tid >> 4, bn4 = (tid & 15) * 4;
  float acc[4][4] = {};
  for (int kt = 0; kt < KCH / 16; kt++) {
    int k0 = kbase + kt * 16;
    float4 ga = *(const float4*)(catm + (size_t)(m0 + sm) * CATW + k0 + skk4 * 4);
    float4 gb = *(const float4*)(wout + (size_t)(k0 + bkk) * 384 + n0 + bn4);
    __syncthreads();
    As[skk4 * 4 + 0][sm] = ga.x;
    As[skk4 * 4 + 1][sm] = ga.y;
    As[skk4 * 4 + 2][sm] = ga.z;
    As[skk4 * 4 + 3][sm] = ga.w;
    *(float4*)&Bs[bkk][bn4] = gb;
    __syncthreads();
    #pragma unroll
    for (int kk = 0; kk < 16; kk++) {
      float4 av = *(const float4*)&As[kk][ty * 4];
      float4 bv = *(const float4*)&Bs[kk][tx * 4];
      acc[0][0] += av.x * bv.x; acc[0][1] += av.x * bv.y; acc[0][2] += av.x * bv.z; acc[0][3] += av.x * bv.w;
      acc[1][0] += av.y * bv.x; acc[1][1] += av.y * bv.y; acc[1][2] += av.y * bv.z; acc[1][3] += av.y * bv.w;
      acc[2][0] += av.z * bv.x; acc[2][1] += av.z * bv.y; acc[2][2] += av.z * bv.z; acc[2][3] += av.z * bv.w;
      acc[3][0] += av.w * bv.x; acc[3][1] += av.w * bv.y; acc[3][2] += av.w * bv.z; acc[3][3] += av.w * bv.w;
    }
  }
  float* pdst = pout + (size_t)blockIdx.z * (1024 * 384);
  #pragma unroll
  for (int mm = 0; mm < 4; mm++) {
    *(float4*)&pdst[(size_t)(m0 + ty * 4 + mm) * 384 + n0 + tx * 4] =
        make_float4(acc[mm][0], acc[mm][1], acc[mm][2], acc[mm][3]);
  }
}

// ---------------- Kernel 5: split-K reduce + bias ----
__global__ void k_red(const float* __restrict__ pout,
                      const float* __restrict__ bout,
                      float* __restrict__ out) {
  int idx = blockIdx.x * 256 + threadIdx.x;
  const int TOTAL = 1024 * 384;
  float s = pout[idx] + pout[TOTAL + idx] + pout[2 * TOTAL + idx] + pout[3 * TOTAL + idx];
  out[idx] = s + bout[idx % 384];
}

extern "C" void kernel_launch(void* const* d_in, const int* in_sizes, int n_in,
                              void* d_out, int out_size, void* d_ws, size_t ws_size,
                              hipStream_t stream) {
  const float* s_i   = (const float*)d_in[0];
  const float* z     = (const float*)d_in[1];
  const float* rots  = (const float*)d_in[2];
  const float* trans = (const float*)d_in[3];
  const float* wq    = (const float*)d_in[4];
  const float* wk    = (const float*)d_in[5];
  const float* wv    = (const float*)d_in[6];
  const float* wqp   = (const float*)d_in[7];
  const float* wkp   = (const float*)d_in[8];
  const float* wvp   = (const float*)d_in[9];
  const float* wb    = (const float*)d_in[10];
  const float* gamma = (const float*)d_in[11];
  const float* wout  = (const float*)d_in[12];
  const float* bout  = (const float*)d_in[13];
  float* out = (float*)d_out;

  float* ws = (float*)d_ws;
  const size_t TOK = (size_t)BB * NN;  // 1024
  float* qw  = ws;                      // TOK*192
  float* kw  = qw + TOK * 192;
  float* vw  = kw + TOK * 192;
  float* tqw = vw + TOK * 192;          // TOK*144
  float* tkw = tqw + TOK * 144;
  float* tvw = tkw + TOK * 144;         // TOK*288
  float* bw  = tvw + TOK * 288;         // TOK*H*N bias
  float* catm = bw + TOK * HH * NN;     // TOK*2112
  float* pout = catm + TOK * CATW;      // 4*1024*384

  k_proj<<<BB * NN / 2, 256, 0, stream>>>(s_i, rots, trans, wq, wk, wv, wqp, wkp, wvp,
                                          qw, kw, vw, tqw, tkw, tvw);
  k_bias<<<BB * NN * NN / 256, 256, 0, stream>>>(z, wb, bw);
  k_att<<<BB * NN, 256, 0, stream>>>(z, qw, kw, tqw, tkw, vw, tvw, gamma, rots, trans,
                                     bw, catm);
  dim3 gg(6, 16, 4);
  k_gemm<<<gg, 256, 0, stream>>>(catm, wout, pout);
  k_red<<<(1024 * 384) / 256, 256, 0, stream>>>(pout, bout, out);
}